// Round 7
// baseline (742.726 us; speedup 1.0000x reference)
//
#include <hip/hip_runtime.h>
#include <math.h>

// ---------------- constants ----------------
#define FH 200
#define FW 200
#define HW 40000            // FH*FW
#define NUM_A 9
#define NANCH 360000        // HW*NUM_A
#define PRE_K 2000
#define OUT_K 1000
#define IMG_SZ 1600.0f
#define MIN_SZ 16.0f
#define NMS_TH 0.7f
#define BBOX_CLIP_F 4.135166556742356f   // log(1000/16)

// ---------------- workspace layout (bytes), total ~11.4 MB ----------------
#define OFF_HIST   ((size_t)0)           // 256 u32 = 1024
#define OFF_STATE  ((size_t)1024)        // 16 u32 = 64
#define OFF_CAND   ((size_t)1088)        // 4096 u64 = 32,768 -> 33,856
#define OFF_BOXS   ((size_t)33856)       // 2000*4 f = 32,000 -> 65,856
#define OFF_SCS    ((size_t)65856)       // 2000 f = 8,000 -> 73,856
#define OFF_MASK   ((size_t)73856)       // 2000*32 u64 = 512,000 -> 585,856
#define OFF_DIAG   ((size_t)585856)      // 2048 u64 = 16,384 -> 602,240
#define OFF_AWH    ((size_t)602240)      // 16*9*8*64*16B = 1,179,648
#define OFF_AWM    ((size_t)1781888)
#define OFF_AWL    ((size_t)2961536)
#define OFF_HWH    ((size_t)4141184)     // 3*8*64*16B = 24,576
#define OFF_HWM    ((size_t)4165760)
#define OFF_HWL    ((size_t)4190336)
#define OFF_PROP   ((size_t)4214912)     // 360000*4 f = 5,760,000 -> 9,974,912
#define OFF_SCORE  ((size_t)9974912)     // 360000 f = 1,440,000 -> 11,414,912

typedef __attribute__((ext_vector_type(8))) short short8;
typedef __attribute__((ext_vector_type(4))) float floatx4;
#define MFMA16(a, b, c) __builtin_amdgcn_mfma_f32_16x16x32_bf16(a, b, c, 0, 0, 0)

__device__ __forceinline__ unsigned short rne_bf16(float v) {
  unsigned int bb = __float_as_uint(v);
  return (unsigned short)((bb + 0x7FFFu + ((bb >> 16) & 1u)) >> 16);
}

// 3-way split: v = h + m + l + eps, |eps| <~ 2^-25 |v|
__device__ __forceinline__ void split3(float v, unsigned short& h,
                                       unsigned short& m, unsigned short& l) {
  h = rne_bf16(v);
  float r1 = v - __uint_as_float(((unsigned int)h) << 16);
  m = rne_bf16(r1);
  float r2 = r1 - __uint_as_float(((unsigned int)m) << 16);
  l = rne_bf16(r2);
}

// =====================================================================
// Prepass: swizzle conv weights + head weights into MFMA A-fragment
// order, 3-way bf16 split (hi/mid/lo planes).  UNCHANGED from R4.
// =====================================================================
__global__ __launch_bounds__(256) void prep_weights(
    const float* __restrict__ w, const float* __restrict__ cls_w,
    const float* __restrict__ reg_w, uint4* __restrict__ AW_h,
    uint4* __restrict__ AW_m, uint4* __restrict__ AW_l,
    uint4* __restrict__ HwF_h, uint4* __restrict__ HwF_m,
    uint4* __restrict__ HwF_l) {
  int gid = blockIdx.x * 256 + threadIdx.x;
  unsigned short h[8], m[8], l[8];
  if (gid < 73728) {
    int L = gid & 63;
    int idx = gid >> 6;            // (ctg*9+tap)*8 + cib
    int cib = idx & 7;
    int tmp = idx >> 3;
    int tap = tmp % 9;
    int ctg = tmp / 9;
    int co = ctg * 16 + (L & 15);
    int ci0 = cib * 32 + (L >> 4) * 8;
#pragma unroll
    for (int j = 0; j < 8; ++j)
      split3(w[(size_t)co * 2304 + (ci0 + j) * 9 + tap], h[j], m[j], l[j]);
    uint4 vh, vm, vl;
    vh.x = h[0] | (h[1] << 16); vh.y = h[2] | (h[3] << 16);
    vh.z = h[4] | (h[5] << 16); vh.w = h[6] | (h[7] << 16);
    vm.x = m[0] | (m[1] << 16); vm.y = m[2] | (m[3] << 16);
    vm.z = m[4] | (m[5] << 16); vm.w = m[6] | (m[7] << 16);
    vl.x = l[0] | (l[1] << 16); vl.y = l[2] | (l[3] << 16);
    vl.z = l[4] | (l[5] << 16); vl.w = l[6] | (l[7] << 16);
    AW_h[gid] = vh; AW_m[gid] = vm; AW_l[gid] = vl;
  } else if (gid < 73728 + 1536) {
    int g2 = gid - 73728;
    int L = g2 & 63;
    int idx = g2 >> 6;             // mt*8 + kb
    int kb = idx & 7;
    int mt = idx >> 3;
    int mm = mt * 16 + (L & 15);
    int co0 = kb * 32 + (L >> 4) * 8;
#pragma unroll
    for (int j = 0; j < 8; ++j) {
      float v = 0.f;
      if (mm < 9) v = cls_w[mm * 256 + co0 + j];
      else if (mm < 45) v = reg_w[(mm - 9) * 256 + co0 + j];
      split3(v, h[j], m[j], l[j]);
    }
    uint4 vh, vm, vl;
    vh.x = h[0] | (h[1] << 16); vh.y = h[2] | (h[3] << 16);
    vh.z = h[4] | (h[5] << 16); vh.w = h[6] | (h[7] << 16);
    vm.x = m[0] | (m[1] << 16); vm.y = m[2] | (m[3] << 16);
    vm.z = m[4] | (m[5] << 16); vm.w = m[6] | (m[7] << 16);
    vl.x = l[0] | (l[1] << 16); vl.y = l[2] | (l[3] << 16);
    vl.z = l[4] | (l[5] << 16); vl.w = l[6] | (l[7] << 16);
    HwF_h[g2] = vh; HwF_m[g2] = vm; HwF_l[g2] = vl;
  }
}

// =====================================================================
// Main fused conv+heads+finalize kernel.
// Block tile: FULL 256 co x 64 px (4 rows x 16 cols).  Grid 13x50.
// 4 waves; wave wv owns co-tiles wv*4..wv*4+3 (64 co) x all 4 px rows.
// 3 B-reads serve 24 MFMA (2x better than R6's 12).  Full K in-block ->
// heads GEMM (2 co-half passes) + anchors/deltas/sigmoid fused in
// epilogue; prop/score written directly (no logits buffer, no atomics).
// Accumulation order per output is bit-identical to R4/R6.
// =====================================================================
__global__ __launch_bounds__(256) void conv_mfma(
    const float* __restrict__ feat, const uint4* __restrict__ AW_h,
    const uint4* __restrict__ AW_m, const uint4* __restrict__ AW_l,
    const uint4* __restrict__ HwF_h, const uint4* __restrict__ HwF_m,
    const uint4* __restrict__ HwF_l, const float* __restrict__ bias,
    const float* __restrict__ cls_b, const float* __restrict__ reg_b,
    float* __restrict__ prop, float* __restrict__ score) {
  __shared__ alignas(16) unsigned short smem[26112];  // 52,224 B
  const int t = threadIdx.x;
  const int L = t & 63, wv = t >> 6;
  const int q = L >> 4, nl = L & 15;
  const int w0 = blockIdx.x * 16;
  const int h0 = blockIdx.y * 4;

  floatx4 acc[4][4];  // [ct][r]
#pragma unroll
  for (int ct = 0; ct < 4; ++ct)
#pragma unroll
    for (int r = 0; r < 4; ++r) acc[ct][r] = (floatx4)0.f;

  unsigned short* flh = smem;          // [6 rows][18 cols][40 ci-pad] u16
  unsigned short* flm = smem + 4320;
  unsigned short* fll = smem + 8640;

  for (int cib = 0; cib < 8; ++cib) {
    __syncthreads();
    // stage 32ci x 6row x 18col fp32 -> split3 -> 3 LDS planes (3456 elems)
#pragma unroll
    for (int j = 0; j < 14; ++j) {
      int e = j * 256 + t;
      if (e < 3456) {
        int ci = e / 108;
        int rem = e - ci * 108;
        int rr = rem / 18;
        int cc = rem - rr * 18;
        int gr = h0 - 1 + rr, gc = w0 - 1 + cc;
        float v = 0.f;
        if ((unsigned)gr < (unsigned)FH && (unsigned)gc < (unsigned)FW)
          v = feat[(size_t)(cib * 32 + ci) * HW + gr * FW + gc];
        unsigned short hh, mm, ll;
        split3(v, hh, mm, ll);
        int off = (rr * 18 + cc) * 40 + ci;
        flh[off] = hh; flm[off] = mm; fll[off] = ll;
      }
    }
    __syncthreads();
    for (int kh = 0; kh < 3; ++kh) {
      for (int kw = 0; kw < 3; ++kw) {
        const int tap = kh * 3 + kw;
        short8 ah[4], am[4], al[4];
#pragma unroll
        for (int ct = 0; ct < 4; ++ct) {
          const int abase = (((wv * 4 + ct) * 9 + tap) * 8 + cib) * 64 + L;
          ah[ct] = ((const short8*)AW_h)[abase];
          am[ct] = ((const short8*)AW_m)[abase];
          al[ct] = ((const short8*)AW_l)[abase];
        }
        const int cbase = (nl + kw) * 40 + q * 8;
#pragma unroll
        for (int r = 0; r < 4; ++r) {
          const int off = (r + kh) * 720 + cbase;
          short8 bh = *(const short8*)(flh + off);
          short8 bm = *(const short8*)(flm + off);
          short8 bl = *(const short8*)(fll + off);
#pragma unroll
          for (int ct = 0; ct < 4; ++ct) {
            acc[ct][r] = MFMA16(ah[ct], bh, acc[ct][r]);
            acc[ct][r] = MFMA16(ah[ct], bm, acc[ct][r]);
            acc[ct][r] = MFMA16(am[ct], bh, acc[ct][r]);
            acc[ct][r] = MFMA16(ah[ct], bl, acc[ct][r]);
            acc[ct][r] = MFMA16(am[ct], bm, acc[ct][r]);
            acc[ct][r] = MFMA16(al[ct], bh, acc[ct][r]);
          }
        }
      }
    }
  }

  // ---- epilogue: bias+ReLU, x -> LDS (per co-half), head GEMM ----
  float bv[4][4];
#pragma unroll
  for (int ct = 0; ct < 4; ++ct)
#pragma unroll
    for (int i = 0; i < 4; ++i)
      bv[ct][i] = bias[(wv * 4 + ct) * 16 + q * 4 + i];

  unsigned short* xlh = smem;           // [64 px][136 co-half-pad] u16
  unsigned short* xlm = smem + 8704;
  unsigned short* xll = smem + 17408;

  floatx4 ha[3];
#pragma unroll
  for (int mt = 0; mt < 3; ++mt) ha[mt] = (floatx4)0.f;

  for (int pass = 0; pass < 2; ++pass) {
    __syncthreads();  // prior smem reads complete
    if ((wv >> 1) == pass) {
#pragma unroll
      for (int ct = 0; ct < 4; ++ct) {
#pragma unroll
        for (int r = 0; r < 4; ++r) {
          unsigned short xh[4], xm[4], xl_[4];
#pragma unroll
          for (int i = 0; i < 4; ++i) {
            float xv = fmaxf(acc[ct][r][i] + bv[ct][i], 0.f);
            split3(xv, xh[i], xm[i], xl_[i]);
          }
          int px_l = r * 16 + nl;
          int co_l = ((wv & 1) * 4 + ct) * 16 + q * 4;
          uint2 ph, pm, pl;
          ph.x = xh[0] | (xh[1] << 16); ph.y = xh[2] | (xh[3] << 16);
          pm.x = xm[0] | (xm[1] << 16); pm.y = xm[2] | (xm[3] << 16);
          pl.x = xl_[0] | (xl_[1] << 16); pl.y = xl_[2] | (xl_[3] << 16);
          *(uint2*)(xlh + px_l * 136 + co_l) = ph;
          *(uint2*)(xlm + px_l * 136 + co_l) = pm;
          *(uint2*)(xll + px_l * 136 + co_l) = pl;
        }
      }
    }
    __syncthreads();
    // head GEMM: wave wv -> px tile wv (16 px); K = this co half (128)
    for (int ks = 0; ks < 4; ++ks) {
      const int boff = (wv * 16 + nl) * 136 + ks * 32 + q * 8;
      short8 bh = *(const short8*)(xlh + boff);
      short8 bm = *(const short8*)(xlm + boff);
      short8 bl = *(const short8*)(xll + boff);
#pragma unroll
      for (int mt = 0; mt < 3; ++mt) {
        const int hb = (mt * 8 + pass * 4 + ks) * 64 + L;
        short8 hh = ((const short8*)HwF_h)[hb];
        short8 hm = ((const short8*)HwF_m)[hb];
        short8 hl = ((const short8*)HwF_l)[hb];
        ha[mt] = MFMA16(hh, bh, ha[mt]);
        ha[mt] = MFMA16(hh, bm, ha[mt]);
        ha[mt] = MFMA16(hm, bh, ha[mt]);
        ha[mt] = MFMA16(hh, bl, ha[mt]);
        ha[mt] = MFMA16(hm, bm, ha[mt]);
        ha[mt] = MFMA16(hl, bh, ha[mt]);
      }
    }
  }

  // ---- scatter logits to LDS, then fused finalize ----
  __syncthreads();
  float* lg = (float*)smem;  // [64 px][52 pad]
#pragma unroll
  for (int mt = 0; mt < 3; ++mt)
#pragma unroll
    for (int i = 0; i < 4; ++i) {
      int head = mt * 16 + q * 4 + i;
      if (head < 45) lg[(wv * 16 + nl) * 52 + head] = ha[mt][i];
    }
  __syncthreads();

  const float scv[3] = {128.f, 256.f, 512.f};
  const float arv[3] = {0.5f, 1.f, 2.f};
  for (int s = t; s < 576; s += 256) {
    int px_l = s / 9;
    int a = s - px_l * 9;
    int r = px_l >> 4, c = px_l & 15;
    int gc = w0 + c;
    if (gc >= FW) continue;
    int px = (h0 + r) * FW + gc;
    int ai = a / 3, si = a % 3;
    float hr = sqrtf(arv[ai]);
    float wr = 1.0f / hr;
    float rw = nearbyintf(wr * scv[si] * 0.5f);
    float rh = nearbyintf(hr * scv[si] * 0.5f);
    float sx = (float)c * 8.0f + (float)w0 * 8.0f;
    float sy = (float)(h0 + r) * 8.0f;
    float ax0 = sx - rw, ay0 = sy - rh, ax1 = sx + rw, ay1 = sy + rh;
    float aw = ax1 - ax0, ah2 = ay1 - ay0;
    float cx = ax0 + 0.5f * aw, cy = ay0 + 0.5f * ah2;
    const float* A = &lg[px_l * 52];
    float dx = A[9 + a * 4 + 0] + reg_b[a * 4 + 0];
    float dy = A[9 + a * 4 + 1] + reg_b[a * 4 + 1];
    float dw = fminf(A[9 + a * 4 + 2] + reg_b[a * 4 + 2], BBOX_CLIP_F);
    float dh = fminf(A[9 + a * 4 + 3] + reg_b[a * 4 + 3], BBOX_CLIP_F);
    float pcx = dx * aw + cx;
    float pcy = dy * ah2 + cy;
    float pw = expf(dw) * aw;
    float ph = expf(dh) * ah2;
    float4 pv;
    pv.x = pcx - 0.5f * pw;
    pv.y = pcy - 0.5f * ph;
    pv.z = pcx + 0.5f * pw;
    pv.w = pcy + 0.5f * ph;
    *(float4*)(prop + (size_t)(px * NUM_A + a) * 4) = pv;
    float lgt = A[a] + cls_b[a];
    score[px * NUM_A + a] = 1.0f / (1.0f + expf(-lgt));
  }
}

// =====================================================================
// Radix select (4 passes of 8 bits) for exact top-2000 threshold.
// Wave-aggregated histogram: one atomicAdd per distinct bucket per wave
// (scores cluster -> few distinct buckets -> kills LDS-atomic serialization)
// =====================================================================
__global__ __launch_bounds__(256) void hist_kernel(
    const float* __restrict__ score, unsigned int* __restrict__ hist,
    const unsigned int* __restrict__ state, int pass) {
  __shared__ unsigned int h[256];
  int t = threadIdx.x;
  int lane = t & 63;
  h[t] = 0;
  __syncthreads();
  unsigned int prefix = (pass == 0) ? 0u : state[0];
  int shift = 24 - 8 * pass;
  for (int i = blockIdx.x * 256 + t; i < NANCH; i += gridDim.x * 256) {
    unsigned int key = __float_as_uint(score[i]);
    bool m = (pass == 0) || ((key >> (32 - 8 * pass)) == prefix);
    unsigned int bkt = (key >> shift) & 255u;
    unsigned long long active = __ballot(m);
    while (active) {
      int lead = __ffsll(active) - 1;
      unsigned int b = __shfl(bkt, lead);
      unsigned long long same = __ballot(m && (bkt == b));
      active &= ~same;
      if (lane == lead) atomicAdd(&h[b], (unsigned int)__popcll(same));
    }
  }
  __syncthreads();
  if (h[t]) atomicAdd(&hist[t], h[t]);
}

__global__ __launch_bounds__(256) void scan_kernel(
    unsigned int* __restrict__ hist, unsigned int* __restrict__ state, int pass) {
  __shared__ unsigned int s0[256], s1[256];
  int t = threadIdx.x;
  unsigned int hv = hist[t];
  hist[t] = 0u;
  s0[t] = hv;
  __syncthreads();
  unsigned int* A = s0;
  unsigned int* B = s1;
  for (int off = 1; off < 256; off <<= 1) {
    B[t] = A[t] + ((t + off < 256) ? A[t + off] : 0u);
    __syncthreads();
    unsigned int* tmp = A; A = B; B = tmp;
  }
  unsigned int prefix = (pass == 0) ? 0u : state[0];
  unsigned int rem = (pass == 0) ? (unsigned)PRE_K : state[1];
  unsigned int suf = A[t];
  unsigned int sufn = (t < 255) ? A[t + 1] : 0u;
  if (suf >= rem && sufn < rem) {
    state[0] = (prefix << 8) | (unsigned int)t;
    state[1] = rem - sufn;
  }
}

__global__ __launch_bounds__(256) void collect_kernel(
    const float* __restrict__ score, unsigned int* __restrict__ state,
    unsigned long long* __restrict__ cand) {
  unsigned int T = state[0];
  for (int i = blockIdx.x * 256 + threadIdx.x; i < NANCH; i += gridDim.x * 256) {
    unsigned int key = __float_as_uint(score[i]);
    if (key >= T) {
      unsigned int pos = atomicAdd(&state[4], 1u);
      if (pos < 4096u)
        cand[pos] = ((unsigned long long)key << 32) |
                    (unsigned long long)(~(unsigned int)i);
    }
  }
}

// =====================================================================
// Bitonic sort + gather + clip + valid + stable partition
// =====================================================================
__global__ __launch_bounds__(1024) void sort_gather(
    const unsigned long long* __restrict__ cand,
    const unsigned int* __restrict__ state, const float* __restrict__ prop,
    const float* __restrict__ score, float* __restrict__ boxes_s,
    float* __restrict__ sc_s) {
  __shared__ unsigned long long sk[4096];
  int t = threadIdx.x;
  unsigned int cnt = state[4];
  if (cnt > 4096u) cnt = 4096u;
  for (int e = t; e < 4096; e += 1024) sk[e] = (e < (int)cnt) ? cand[e] : 0ull;
  __syncthreads();
  for (int k = 2; k <= 4096; k <<= 1) {
    for (int j = k >> 1; j > 0; j >>= 1) {
      for (int i = t; i < 4096; i += 1024) {
        int l = i ^ j;
        if (l > i) {
          unsigned long long a = sk[i], bb = sk[l];
          bool up = ((i & k) == 0);
          bool sw = up ? (a < bb) : (a > bb);
          if (sw) { sk[i] = bb; sk[l] = a; }
        }
      }
      __syncthreads();
    }
  }
  float bx[2][4];
  float sc2[2] = {-1.f, -1.f};
  bool valid2[2] = {false, false};
#pragma unroll
  for (int s = 0; s < 2; ++s) {
    int i = t + s * 1024;
    bx[s][0] = bx[s][1] = bx[s][2] = bx[s][3] = 0.f;
    if (i < PRE_K) {
      unsigned long long v = sk[i];
      unsigned int idx = ~(unsigned int)(v & 0xFFFFFFFFull);
      float4 p = *(const float4*)(prop + (size_t)idx * 4);
      float x0 = fminf(fmaxf(p.x, 0.f), IMG_SZ);
      float y0 = fminf(fmaxf(p.y, 0.f), IMG_SZ);
      float x1 = fminf(fmaxf(p.z, 0.f), IMG_SZ);
      float y1 = fminf(fmaxf(p.w, 0.f), IMG_SZ);
      bool valid = (x1 - x0 >= MIN_SZ) && (y1 - y0 >= MIN_SZ);
      bx[s][0] = x0; bx[s][1] = y0; bx[s][2] = x1; bx[s][3] = y1;
      valid2[s] = valid;
      sc2[s] = valid ? score[idx] : -1.0f;
    }
  }
  __syncthreads();
  int* A = (int*)sk;
  int* B = A + 2048;
#pragma unroll
  for (int s = 0; s < 2; ++s) {
    int i = t + s * 1024;
    A[i] = (i < PRE_K && valid2[s]) ? 1 : 0;
  }
  __syncthreads();
  for (int off = 1; off < 2048; off <<= 1) {
#pragma unroll
    for (int s = 0; s < 2; ++s) {
      int i = t + s * 1024;
      B[i] = A[i] + ((i >= off) ? A[i - off] : 0);
    }
    __syncthreads();
    int* tmp = A; A = B; B = tmp;
  }
  int total = A[2047];
#pragma unroll
  for (int s = 0; s < 2; ++s) {
    int i = t + s * 1024;
    if (i < PRE_K) {
      int inc = A[i];
      int pos = valid2[s] ? (inc - 1) : (total + (i - inc));
      boxes_s[pos * 4 + 0] = bx[s][0];
      boxes_s[pos * 4 + 1] = bx[s][1];
      boxes_s[pos * 4 + 2] = bx[s][2];
      boxes_s[pos * 4 + 3] = bx[s][3];
      sc_s[pos] = sc2[s];
    }
  }
}

// =====================================================================
// IoU suppression bitmask (+ coalesced diag words)
// =====================================================================
__global__ __launch_bounds__(64) void iou_kernel(
    const float* __restrict__ boxes_s, unsigned long long* __restrict__ mask,
    unsigned long long* __restrict__ diag) {
  int bi = blockIdx.y, bj = blockIdx.x;
  int t = threadIdx.x;
  __shared__ float4 cb[64];
  int jc = bj * 64 + t;
  float4 z; z.x = z.y = z.z = z.w = 0.f;
  cb[t] = (jc < PRE_K) ? *(const float4*)(boxes_s + (size_t)jc * 4) : z;
  __syncthreads();
  int i = bi * 64 + t;
  if (i >= PRE_K) return;
  float4 a = *(const float4*)(boxes_s + (size_t)i * 4);
  float areaA = (a.z - a.x) * (a.w - a.y);
  unsigned long long bits = 0ull;
  for (int jj = 0; jj < 64; ++jj) {
    int j = bj * 64 + jj;
    if (j < PRE_K && j > i) {
      float4 b = cb[jj];
      float areaB = (b.z - b.x) * (b.w - b.y);
      float ltx = fmaxf(a.x, b.x), lty = fmaxf(a.y, b.y);
      float rbx = fminf(a.z, b.z), rby = fminf(a.w, b.w);
      float w = fmaxf(rbx - ltx, 0.f), h = fmaxf(rby - lty, 0.f);
      float inter = w * h;
      float iou = inter / (areaA + areaB - inter + 1e-9f);
      if (iou > NMS_TH) bits |= (1ull << jj);
    }
  }
  mask[(size_t)i * 32 + bj] = bits;
  if (bi == bj) diag[i] = bits;
}

// =====================================================================
// Block-resolved sequential NMS + final compaction to d_out (R5 version)
// =====================================================================
__global__ __launch_bounds__(256) void nms_out_kernel(
    const float* __restrict__ boxes_s, const float* __restrict__ sc_s,
    const unsigned long long* __restrict__ mask,
    const unsigned long long* __restrict__ diag, float* __restrict__ out) {
  int t = threadIdx.x;
  for (int e = t; e < (OUT_K * 4 + OUT_K); e += 256) out[e] = 0.f;
  __shared__ unsigned long long keepw[32];
  if (t < 64) {
    unsigned long long removed = 0ull;  // lanes 0..31 own word t
    if (t < 32) {
      keepw[t] = 0ull;
#pragma unroll
      for (int k = 0; k < 64; ++k) {
        int idx = t * 64 + k;
        if (idx >= PRE_K || sc_s[idx] < 0.f) removed |= (1ull << k);
      }
    }
    const int w = t & 31;
    const int half = t >> 5;
    unsigned int kept = 0;
    for (int b = 0; b < 32; ++b) {
      unsigned long long d = diag[b * 64 + t];  // coalesced 512B
      unsigned long long dead = __shfl(removed, b);
      unsigned long long alive = 0ull;
#pragma unroll
      for (int k = 0; k < 64; ++k) {
        unsigned long long dk = __shfl(d, k);
        if (!((dead >> k) & 1ull)) {
          alive |= (1ull << k);
          dead |= dk;
        }
      }
      if (t == 0) keepw[b] = alive;
      kept += (unsigned)__popcll(alive);
      if (kept >= (unsigned)OUT_K || b == 31) break;
      unsigned long long am = alive;
      const long long rb = (long long)b * 64;
      while (am) {
        int k0 = __ffsll(am) - 1; am &= am - 1;
        int k1 = k0, k2 = k0, k3 = k0, k4 = k0, k5 = k0, k6 = k0, k7 = k0;
        if (am) { k1 = __ffsll(am) - 1; am &= am - 1; }
        if (am) { k2 = __ffsll(am) - 1; am &= am - 1; }
        if (am) { k3 = __ffsll(am) - 1; am &= am - 1; }
        if (am) { k4 = __ffsll(am) - 1; am &= am - 1; }
        if (am) { k5 = __ffsll(am) - 1; am &= am - 1; }
        if (am) { k6 = __ffsll(am) - 1; am &= am - 1; }
        if (am) { k7 = __ffsll(am) - 1; am &= am - 1; }
        unsigned long long v0 = mask[(size_t)(rb + (half ? k1 : k0)) * 32 + w];
        unsigned long long v1 = mask[(size_t)(rb + (half ? k3 : k2)) * 32 + w];
        unsigned long long v2 = mask[(size_t)(rb + (half ? k5 : k4)) * 32 + w];
        unsigned long long v3 = mask[(size_t)(rb + (half ? k7 : k6)) * 32 + w];
        unsigned long long vv = v0 | v1 | v2 | v3;
        unsigned long long hv = __shfl(vv, w + 32);
        if (t < 32) removed |= vv | hv;
      }
    }
  }
  __syncthreads();
  __shared__ unsigned int wbase[32];
  if (t == 0) {
    unsigned int s = 0;
    for (int k = 0; k < 32; ++k) {
      wbase[k] = s;
      s += (unsigned)__popcll(keepw[k]);
    }
  }
  __syncthreads();
  for (int i = t; i < PRE_K; i += 256) {
    unsigned long long w2 = keepw[i >> 6];
    if ((w2 >> (i & 63)) & 1ull) {
      unsigned int pos =
          wbase[i >> 6] +
          (unsigned)__popcll(w2 & ((1ull << (i & 63)) - 1ull));
      if (pos < OUT_K) {
        out[pos * 4 + 0] = boxes_s[i * 4 + 0];
        out[pos * 4 + 1] = boxes_s[i * 4 + 1];
        out[pos * 4 + 2] = boxes_s[i * 4 + 2];
        out[pos * 4 + 3] = boxes_s[i * 4 + 3];
        out[OUT_K * 4 + pos] = sc_s[i];
      }
    }
  }
}

// =====================================================================
extern "C" void kernel_launch(void* const* d_in, const int* in_sizes, int n_in,
                              void* d_out, int out_size, void* d_ws,
                              size_t ws_size, hipStream_t stream) {
  const float* feat = (const float*)d_in[1];
  const float* convw = (const float*)d_in[2];
  const float* convb = (const float*)d_in[3];
  const float* clsw = (const float*)d_in[4];
  const float* clsb = (const float*)d_in[5];
  const float* regw = (const float*)d_in[6];
  const float* regb = (const float*)d_in[7];

  char* ws = (char*)d_ws;
  unsigned int* hist = (unsigned int*)(ws + OFF_HIST);
  unsigned int* state = (unsigned int*)(ws + OFF_STATE);
  unsigned long long* cand = (unsigned long long*)(ws + OFF_CAND);
  float* boxes_s = (float*)(ws + OFF_BOXS);
  float* sc_s = (float*)(ws + OFF_SCS);
  unsigned long long* mask = (unsigned long long*)(ws + OFF_MASK);
  unsigned long long* diag = (unsigned long long*)(ws + OFF_DIAG);
  uint4* AW_h = (uint4*)(ws + OFF_AWH);
  uint4* AW_m = (uint4*)(ws + OFF_AWM);
  uint4* AW_l = (uint4*)(ws + OFF_AWL);
  uint4* HwF_h = (uint4*)(ws + OFF_HWH);
  uint4* HwF_m = (uint4*)(ws + OFF_HWM);
  uint4* HwF_l = (uint4*)(ws + OFF_HWL);
  float* prop = (float*)(ws + OFF_PROP);
  float* score = (float*)(ws + OFF_SCORE);
  float* out = (float*)d_out;

  // zero hist + state (1088 B prefix)
  hipMemsetAsync(ws, 0, 1088, stream);

  prep_weights<<<294, 256, 0, stream>>>(convw, clsw, regw, AW_h, AW_m, AW_l,
                                        HwF_h, HwF_m, HwF_l);
  conv_mfma<<<dim3(13, 50), 256, 0, stream>>>(feat, AW_h, AW_m, AW_l, HwF_h,
                                              HwF_m, HwF_l, convb, clsb, regb,
                                              prop, score);
  for (int p = 0; p < 4; ++p) {
    hist_kernel<<<256, 256, 0, stream>>>(score, hist, state, p);
    scan_kernel<<<1, 256, 0, stream>>>(hist, state, p);
  }
  collect_kernel<<<256, 256, 0, stream>>>(score, state, cand);
  sort_gather<<<1, 1024, 0, stream>>>(cand, state, prop, score, boxes_s, sc_s);
  iou_kernel<<<dim3(32, 32), 64, 0, stream>>>(boxes_s, mask, diag);
  nms_out_kernel<<<1, 256, 0, stream>>>(boxes_s, sc_s, mask, diag, out);
}